// Round 17
// baseline (942.041 us; speedup 1.0000x reference)
//
#include <hip/hip_runtime.h>

typedef unsigned short ushort_t;
typedef __attribute__((ext_vector_type(4))) float f32x4;
typedef __attribute__((ext_vector_type(8))) __bf16 bf16x8;
typedef __attribute__((ext_vector_type(4))) unsigned short ushort4_t;
typedef __attribute__((ext_vector_type(8))) unsigned short ushort8_t;
typedef __attribute__((ext_vector_type(2))) unsigned int u32x2;

#define AS1 __attribute__((address_space(1)))
#define AS3 __attribute__((address_space(3)))

__device__ __forceinline__ float bf2f(ushort_t u) {
  unsigned int v = ((unsigned int)u) << 16;
  return __builtin_bit_cast(float, v);
}
__device__ __forceinline__ ushort_t f2bf(float f) {
  unsigned int u = __builtin_bit_cast(unsigned int, f);
  u += 0x7fffu + ((u >> 16) & 1u);
  return (ushort_t)(u >> 16);
}
__device__ __forceinline__ void storeC(float* p, float v) { *p = v; }
__device__ __forceinline__ void storeC(ushort_t* p, float v) { *p = f2bf(v); }

// ---------------------------------------------------------------- elementwise
__global__ __launch_bounds__(256) void cast_f32_bf16(const float* __restrict__ in,
                                                     ushort_t* __restrict__ outp) {
  size_t i = ((size_t)blockIdx.x * 256 + threadIdx.x) * 4;
  f32x4 v = *(const f32x4*)(const void*)&in[i];
  ushort4_t o;
#pragma unroll
  for (int j = 0; j < 4; ++j) o[j] = f2bf(v[j]);
  *(ushort4_t*)(void*)&outp[i] = o;
}

// batched W[K][N] f32 -> Wt[N][K] bf16 (plain)
__global__ __launch_bounds__(256) void transpose_cast_b(
    const float* __restrict__ W0, const float* __restrict__ W1,
    const float* __restrict__ W2, const float* __restrict__ W3,
    ushort_t* __restrict__ Wt, int K, int N, long long strT) {
  __shared__ float tile[32][33];
  const int z = blockIdx.z;
  const float* W = (z == 0) ? W0 : (z == 1) ? W1 : (z == 2) ? W2 : W3;
  ushort_t* out = Wt + (size_t)(strT * z);
  int n0 = blockIdx.x * 32, k0 = blockIdx.y * 32;
  int tx = threadIdx.x, ty = threadIdx.y;
#pragma unroll
  for (int i = 0; i < 4; ++i)
    tile[ty + 8 * i][tx] = W[(size_t)(k0 + ty + 8 * i) * N + n0 + tx];
  __syncthreads();
#pragma unroll
  for (int i = 0; i < 4; ++i)
    out[(size_t)(n0 + ty + 8 * i) * K + k0 + tx] = f2bf(tile[tx][ty + 8 * i]);
}

// gate-weight transpose with 16-col interleave for GLU-fused GEMM
__global__ __launch_bounds__(256) void transpose_cast_glu(
    const float* __restrict__ W1k, const float* __restrict__ W3k,
    const float* __restrict__ W1v, const float* __restrict__ W3v,
    ushort_t* __restrict__ out, long long strT) {
  __shared__ float tile[32][33];
  const int z = blockIdx.z;
  const float* W = (z == 0) ? W1k : (z == 1) ? W3k : (z == 2) ? W1v : W3v;
  ushort_t* o = out + (size_t)((z >> 1) * strT);
  const int zz = z & 1;
  int n0 = blockIdx.x * 32, k0 = blockIdx.y * 32;
  int tx = threadIdx.x, ty = threadIdx.y;
#pragma unroll
  for (int i = 0; i < 4; ++i)
    tile[ty + 8 * i][tx] = W[(size_t)(k0 + ty + 8 * i) * 8192 + n0 + tx];
  __syncthreads();
#pragma unroll
  for (int i = 0; i < 4; ++i) {
    int n = n0 + ty + 8 * i;
    int br = ((n >> 4) * 32) + zz * 16 + (n & 15);
    o[(size_t)br * 2048 + k0 + tx] = f2bf(tile[tx][ty + 8 * i]);
  }
}

// ------------------------------------------------- split-K reduce (bf16 parts)
__global__ __launch_bounds__(256) void reduce_q(const ushort_t* __restrict__ part,
                                                ushort_t* __restrict__ qb,
                                                const float* __restrict__ fc,
                                                const float* __restrict__ fs) {
  const float alpha = 0.08838834764831845f;  // 1/sqrt(128)
  int p = blockIdx.x * 256 + threadIdx.x;
  size_t e0 = (size_t)p * 8;
  int i0 = (int)((e0 & 127) >> 1);
  int s = (int)((e0 >> 11) & 2047);
  ushort8_t a = *(const ushort8_t*)(const void*)&part[e0];
  ushort8_t b = *(const ushort8_t*)(const void*)&part[e0 + 8388608];
  f32x4 c4 = *(const f32x4*)(const void*)&fc[s * 64 + i0];
  f32x4 s4 = *(const f32x4*)(const void*)&fs[s * 64 + i0];
  ushort8_t o;
#pragma unroll
  for (int j = 0; j < 4; ++j) {
    float xr = bf2f(a[2 * j]) + bf2f(b[2 * j]);
    float xi = bf2f(a[2 * j + 1]) + bf2f(b[2 * j + 1]);
    float c = c4[j] * alpha, sn = s4[j] * alpha;
    o[2 * j] = f2bf(xr * c - xi * sn);
    o[2 * j + 1] = f2bf(xr * sn + xi * c);
  }
  *(ushort8_t*)(void*)&qb[e0] = o;
}

__global__ __launch_bounds__(256) void reduce_k(const ushort_t* __restrict__ part,
                                                ushort_t* __restrict__ kb,
                                                float* __restrict__ okeys,
                                                const float* __restrict__ fc,
                                                const float* __restrict__ fs) {
  int p = blockIdx.x * 256 + threadIdx.x;
  size_t e0 = (size_t)p * 8;
  int i0 = (int)((e0 & 127) >> 1);
  int s = (int)((e0 >> 10) & 2047);
  ushort8_t a0 = *(const ushort8_t*)(const void*)&part[e0];
  ushort8_t a1 = *(const ushort8_t*)(const void*)&part[e0 + 4194304];
  ushort8_t a2 = *(const ushort8_t*)(const void*)&part[e0 + 8388608];
  ushort8_t a3 = *(const ushort8_t*)(const void*)&part[e0 + 12582912];
  f32x4 c4 = *(const f32x4*)(const void*)&fc[s * 64 + i0];
  f32x4 s4 = *(const f32x4*)(const void*)&fs[s * 64 + i0];
  ushort8_t o;
  f32x4 ov0, ov1;
#pragma unroll
  for (int j = 0; j < 4; ++j) {
    float xr = bf2f(a0[2 * j]) + bf2f(a1[2 * j]) + bf2f(a2[2 * j]) + bf2f(a3[2 * j]);
    float xi = bf2f(a0[2 * j + 1]) + bf2f(a1[2 * j + 1]) + bf2f(a2[2 * j + 1]) +
               bf2f(a3[2 * j + 1]);
    float c = c4[j], sn = s4[j];
    float orr = xr * c - xi * sn;
    float oi = xr * sn + xi * c;
    o[2 * j] = f2bf(orr);
    o[2 * j + 1] = f2bf(oi);
    if (j < 2) { ov0[2 * j] = orr; ov0[2 * j + 1] = oi; }
    else       { ov1[2 * (j - 2)] = orr; ov1[2 * (j - 2) + 1] = oi; }
  }
  *(ushort8_t*)(void*)&kb[e0] = o;
  *(f32x4*)(void*)&okeys[e0] = ov0;
  *(f32x4*)(void*)&okeys[e0 + 4] = ov1;
}

__global__ __launch_bounds__(256) void reduce_v(const ushort_t* __restrict__ part,
                                                float* __restrict__ ovals,
                                                ushort_t* __restrict__ vbT) {
  __shared__ ushort_t tile[32][33];
  int s0 = blockIdx.x * 32, d0 = blockIdx.y * 32, bk = blockIdx.z;
  int b = bk >> 3, kh = bk & 7;
  int tx = threadIdx.x, ty = threadIdx.y;
#pragma unroll
  for (int i = 0; i < 4; ++i) {
    int s = s0 + ty + 8 * i;
    size_t src = ((size_t)(b * 2048 + s)) * 1024 + kh * 128 + d0 + tx;
    float v = bf2f(part[src]) + bf2f(part[src + 4194304]) +
              bf2f(part[src + 8388608]) + bf2f(part[src + 12582912]);
    tile[ty + 8 * i][tx] = f2bf(v);
    ovals[src] = v;
  }
  __syncthreads();
#pragma unroll
  for (int i = 0; i < 4; ++i) {
    int d = d0 + ty + 8 * i;
    vbT[((size_t)bk * 128 + d) * 2048 + s0 + tx] = tile[tx][ty + 8 * i];
  }
}

// partO: [2][4096][2048] bf16 -> outp f32. 8 elems/thread -> grid 4096 ONLY.
__global__ __launch_bounds__(256) void reduce_wo(const ushort_t* __restrict__ part,
                                                 float* __restrict__ outp) {
  size_t e0 = ((size_t)blockIdx.x * 256 + threadIdx.x) * 8;
  ushort8_t a = *(const ushort8_t*)(const void*)&part[e0];
  ushort8_t b = *(const ushort8_t*)(const void*)&part[e0 + 8388608];
  f32x4 o0, o1;
#pragma unroll
  for (int j = 0; j < 4; ++j) {
    o0[j] = bf2f(a[j]) + bf2f(b[j]);
    o1[j] = bf2f(a[j + 4]) + bf2f(b[j + 4]);
  }
  *(f32x4*)(void*)&outp[e0] = o0;
  *(f32x4*)(void*)&outp[e0 + 4] = o1;
}

// ---------------------------------------------------------------- flash attn
__global__ __launch_bounds__(256) void flash_attn(
    const ushort_t* __restrict__ Q, const ushort_t* __restrict__ Kg,
    const ushort_t* __restrict__ VT, ushort_t* __restrict__ O) {
  __shared__ __align__(16) char smem[81920];
  const int xq = blockIdx.x;
  const int bh = blockIdx.y;
  const int qi = (bh & 16) ? (15 - xq) : xq;
  const int b = bh >> 4, h = bh & 15, kh = h >> 1;
  const int t = threadIdx.x, w = t >> 6, lane = t & 63;
  const int fr = lane & 15, fh = lane >> 4;
  const size_t kelem0 = ((size_t)b * 2048) * 1024 + kh * 128;
  const size_t velem0 = ((size_t)(b * 8 + kh)) * 128 * 2048;
  const size_t qrow0 = (size_t)b * 2048;

  size_t oK[4], oV[4];
#pragma unroll
  for (int qv = 0; qv < 4; ++qv) {
    int row = w * 16 + qv * 4 + (lane >> 4);
    oK[qv] = (size_t)row * 1024 + (((lane & 15) ^ (row & 7)) * 8);
    int rd = w * 32 + qv * 8 + (lane >> 3);
    oV[qv] = (size_t)rd * 2048 + (((lane & 7) ^ (rd & 7)) * 8);
  }

  auto stage = [&](int tile, int buf) {
    const size_t kc = (size_t)tile * 64 * 1024;
    const int vc = tile * 64;
    char* kd = smem + buf * 16384 + w * 4096;
    char* vd = smem + 32768 + buf * 16384 + w * 4096;
#pragma unroll
    for (int qv = 0; qv < 4; ++qv) {
      __builtin_amdgcn_global_load_lds((const AS1 void*)(Kg + kelem0 + kc + oK[qv]),
                                       (AS3 void*)(kd + qv * 1024), 16, 0, 0);
      __builtin_amdgcn_global_load_lds((const AS1 void*)(VT + velem0 + oV[qv] + vc),
                                       (AS3 void*)(vd + qv * 1024), 16, 0, 0);
    }
  };

  const int qw = qi * 128 + w * 32;
  const int nt = 2 * qi + 2;

  bf16x8 qF[2][4];
#pragma unroll
  for (int qt = 0; qt < 2; ++qt)
#pragma unroll
    for (int i = 0; i < 4; ++i)
      qF[qt][i] = *(const bf16x8*)(const void*)(
          Q + (qrow0 + qw + qt * 16 + fr) * 2048 + h * 128 + i * 32 + fh * 8);

  f32x4 acco[8][2] = {};
  float mrun[2] = {-1e30f, -1e30f};
  float lrun[2] = {0.0f, 0.0f};

  stage(0, 0);
#pragma unroll 1
  for (int tt = 0; tt < nt; ++tt) {
    const int c0 = tt * 64;
    if (tt + 1 < nt) {
      stage(tt + 1, (tt + 1) & 1);
      asm volatile("s_waitcnt vmcnt(8)" ::: "memory");
    } else {
      asm volatile("s_waitcnt vmcnt(0)" ::: "memory");
    }
    __builtin_amdgcn_sched_barrier(0);
    __builtin_amdgcn_s_barrier();
    const char* KL = smem + (tt & 1) * 16384;
    const char* VL = smem + 32768 + (tt & 1) * 16384;
    char* PL = smem + 65536 + w * 4096;
    if (c0 <= qw + 31) {
      f32x4 sacc[2][4] = {};
#pragma unroll
      for (int i = 0; i < 4; ++i)
#pragma unroll
        for (int mt = 0; mt < 4; ++mt) {
          bf16x8 kf = *(const bf16x8*)(const void*)(
              KL + (mt * 16 + fr) * 256 + (((i * 4 + fh) ^ (fr & 7)) * 16));
          sacc[0][mt] = __builtin_amdgcn_mfma_f32_16x16x32_bf16(kf, qF[0][i], sacc[0][mt], 0, 0, 0);
          sacc[1][mt] = __builtin_amdgcn_mfma_f32_16x16x32_bf16(kf, qF[1][i], sacc[1][mt], 0, 0, 0);
        }
      if (c0 + 63 > qw) {
#pragma unroll
        for (int qt = 0; qt < 2; ++qt) {
          int qg = qw + qt * 16 + fr;
#pragma unroll
          for (int mt = 0; mt < 4; ++mt)
#pragma unroll
            for (int j = 0; j < 4; ++j)
              if (c0 + mt * 16 + fh * 4 + j > qg) sacc[qt][mt][j] = -1e30f;
        }
      }
#pragma unroll
      for (int qt = 0; qt < 2; ++qt) {
        float mt_ = -1e30f;
#pragma unroll
        for (int mt = 0; mt < 4; ++mt)
#pragma unroll
          for (int j = 0; j < 4; ++j) mt_ = fmaxf(mt_, sacc[qt][mt][j]);
        mt_ = fmaxf(mt_, __shfl_xor(mt_, 16, 64));
        mt_ = fmaxf(mt_, __shfl_xor(mt_, 32, 64));
        float mnew = fmaxf(mrun[qt], mt_);
        float corr = __expf(mrun[qt] - mnew);
        mrun[qt] = mnew;
        float ps = 0.0f;
        float pv[4][4];
#pragma unroll
        for (int mt = 0; mt < 4; ++mt)
#pragma unroll
          for (int j = 0; j < 4; ++j) {
            float pe = __expf(sacc[qt][mt][j] - mnew);
            pv[mt][j] = pe;
            ps += pe;
          }
        ps += __shfl_xor(ps, 16, 64);
        ps += __shfl_xor(ps, 32, 64);
        lrun[qt] = lrun[qt] * corr + ps;
#pragma unroll
        for (int mt = 0; mt < 4; ++mt) {
          unsigned int u0, u1;
          asm("v_cvt_pk_bf16_f32 %0, %1, %2" : "=v"(u0) : "v"(pv[mt][0]), "v"(pv[mt][1]));
          asm("v_cvt_pk_bf16_f32 %0, %1, %2" : "=v"(u1) : "v"(pv[mt][2]), "v"(pv[mt][3]));
          u32x2 val;
          val[0] = u0;
          val[1] = u1;
          *(u32x2*)(void*)(PL + qt * 2048 + fr * 128 +
                           (((2 * mt + (fh >> 1)) ^ (fr & 7)) * 16) + (fh & 1) * 8) = val;
        }
#pragma unroll
        for (int dt = 0; dt < 8; ++dt) acco[dt][qt] *= corr;
      }
      bf16x8 pf[2][2];
#pragma unroll
      for (int qt = 0; qt < 2; ++qt)
#pragma unroll
        for (int ks = 0; ks < 2; ++ks)
          pf[qt][ks] = *(const bf16x8*)(const void*)(
              PL + qt * 2048 + fr * 128 + (((ks * 4 + fh) ^ (fr & 7)) * 16));
#pragma unroll
      for (int dt = 0; dt < 8; ++dt)
#pragma unroll
        for (int ks = 0; ks < 2; ++ks) {
          bf16x8 vf = *(const bf16x8*)(const void*)(
              VL + (dt * 16 + fr) * 128 + (((ks * 4 + fh) ^ (fr & 7)) * 16));
          acco[dt][0] = __builtin_amdgcn_mfma_f32_16x16x32_bf16(vf, pf[0][ks], acco[dt][0], 0, 0, 0);
          acco[dt][1] = __builtin_amdgcn_mfma_f32_16x16x32_bf16(vf, pf[1][ks], acco[dt][1], 0, 0, 0);
        }
    }
    __builtin_amdgcn_s_barrier();
  }
#pragma unroll
  for (int qt = 0; qt < 2; ++qt) {
    float inv = 1.0f / lrun[qt];
    const size_t rb = (qrow0 + qw + qt * 16 + fr) * 2048 + h * 128;
#pragma unroll
    for (int dt = 0; dt < 8; ++dt) {
      ushort4_t o4;
#pragma unroll
      for (int j = 0; j < 4; ++j) o4[j] = f2bf(acco[dt][qt][j] * inv);
      *(ushort4_t*)(void*)(O + rb + dt * 16 + fh * 4) = o4;
    }
  }
}

// ============ m201-style phased schedule (best for K-deep: k2/v2, q, wo) =====
#define GEMM_PHASE(ABUF, BBUF, Q, STAGE_STMT, TAIL_STMT)                        \
  {                                                                             \
    if ((Q) == 0) {                                                             \
      _Pragma("unroll") for (int nf = 0; nf < 4; ++nf) {                        \
        const char* bp = (BBUF) + ((wn * 64 + nf * 16 + fr) << 7);              \
        bF[nf][0] = *(const bf16x8*)(const void*)(bp + sl);                     \
        bF[nf][1] = *(const bf16x8*)(const void*)(bp + (sl ^ 64));              \
      }                                                                         \
    }                                                                           \
    _Pragma("unroll") for (int mi = 0; mi < 2; ++mi) {                          \
      const char* ap = (ABUF) + ((wm * 128 + ((Q)*2 + mi) * 16 + fr) << 7);     \
      aF[mi][0] = *(const bf16x8*)(const void*)(ap + sl);                       \
      aF[mi][1] = *(const bf16x8*)(const void*)(ap + (sl ^ 64));                \
    }                                                                           \
    STAGE_STMT;                                                                 \
    if ((Q) == 0) asm volatile("s_waitcnt lgkmcnt(8)" ::: "memory");            \
    __builtin_amdgcn_s_barrier();                                               \
    asm volatile("s_waitcnt lgkmcnt(0)" ::: "memory");                          \
    __builtin_amdgcn_sched_barrier(0);                                          \
    __builtin_amdgcn_s_setprio(1);                                              \
    _Pragma("unroll") for (int mi = 0; mi < 2; ++mi)                            \
      _Pragma("unroll") for (int nf = 0; nf < 4; ++nf) {                        \
        acc[(Q)*2 + mi][nf] = __builtin_amdgcn_mfma_f32_16x16x32_bf16(          \
            aF[mi][0], bF[nf][0], acc[(Q)*2 + mi][nf], 0, 0, 0);                \
        acc[(Q)*2 + mi][nf] = __builtin_amdgcn_mfma_f32_16x16x32_bf16(          \
            aF[mi][1], bF[nf][1], acc[(Q)*2 + mi][nf], 0, 0, 0);                \
      }                                                                         \
    __builtin_amdgcn_s_setprio(0);                                              \
    TAIL_STMT;                                                                  \
    __builtin_amdgcn_sched_barrier(0);                                          \
    __builtin_amdgcn_s_barrier();                                               \
  }

#define GEMM_BODY_PH                                                            \
  f32x4 acc[8][4] = {};                                                         \
  const int NT = K >> 6;                                                        \
  const int NI = NT >> 1;                                                       \
  char* const A0 = (char*)smem;                                                 \
  char* const A1 = (char*)smem + 32768;                                         \
  char* const B0 = (char*)smem + 65536;                                         \
  char* const B1 = (char*)smem + 98304;                                         \
  auto stageA = [&](int tile, int h) {                                          \
    char* base = (char*)smem + ((tile & 1) << 15);                              \
    const ushort_t* src = gA + tile * 64 + (size_t)(h * 64) * lda;              \
    __builtin_amdgcn_global_load_lds((const AS1 void*)src,                      \
        (AS3 void*)(base + h * 8192 + w * 1024), 16, 0, 0);                     \
    __builtin_amdgcn_global_load_lds(                                           \
        (const AS1 void*)(src + (size_t)128 * lda),                             \
        (AS3 void*)(base + 16384 + h * 8192 + w * 1024), 16, 0, 0);             \
  };                                                                            \
  auto stageB = [&](int tile, int h) {                                          \
    char* base = (char*)smem + 65536 + ((tile & 1) << 15);                      \
    const ushort_t* src = gB + tile * 64 + (size_t)(h * 128) * ldb;             \
    __builtin_amdgcn_global_load_lds((const AS1 void*)src,                      \
        (AS3 void*)(base + h * 16384 + w * 1024), 16, 0, 0);                    \
    __builtin_amdgcn_global_load_lds(                                           \
        (const AS1 void*)(src + (size_t)64 * ldb),                              \
        (AS3 void*)(base + h * 16384 + 8192 + w * 1024), 16, 0, 0);             \
  };                                                                            \
  stageB(0, 0); stageB(0, 1); stageA(0, 0); stageA(0, 1);                       \
  stageB(1, 0); stageB(1, 1); stageA(1, 0);                                     \
  asm volatile("s_waitcnt vmcnt(6)" ::: "memory");                              \
  __builtin_amdgcn_sched_barrier(0);                                            \
  __builtin_amdgcn_s_barrier();                                                 \
  __builtin_amdgcn_sched_barrier(0);                                            \
  for (int i = 0; i < NI; ++i) {                                                \
    const int T1 = 2 * i + 1, T2 = 2 * i + 2, T3 = 2 * i + 3;                   \
    const bool s2 = T2 < NT, s3 = T3 < NT;                                      \
    bf16x8 bF[4][2], aF[2][2];                                                  \
    GEMM_PHASE(A0, B0, 0, { stageA(T1, 1); }, {})                               \
    GEMM_PHASE(A0, B0, 1, { if (s2) stageB(T2, 0); }, {})                       \
    GEMM_PHASE(A0, B0, 2, { if (s2) stageB(T2, 1); }, {})                       \
    GEMM_PHASE(A0, B0, 3, { if (s2) stageA(T2, 0); },                           \
               { if (s2) asm volatile("s_waitcnt vmcnt(6)" ::: "memory");       \
                 else    asm volatile("s_waitcnt vmcnt(0)" ::: "memory"); })    \
    GEMM_PHASE(A1, B1, 0, { if (s2) stageA(T2, 1); }, {})                       \
    GEMM_PHASE(A1, B1, 1, { if (s3) stageB(T3, 0); }, {})                       \
    GEMM_PHASE(A1, B1, 2, { if (s3) stageB(T3, 1); }, {})                       \
    GEMM_PHASE(A1, B1, 3, { if (s3) stageA(T3, 0); },                           \
               { if (s2) asm volatile("s_waitcnt vmcnt(6)" ::: "memory"); })    \
  }

template <typename CT>
__global__ __launch_bounds__(512, 2) void gemm256(
    const ushort_t* __restrict__ A, const ushort_t* __restrict__ B,
    CT* __restrict__ C, int K, int lda, int ldb, int ldc,
    int nwgx, int nwg, long long strA, long long strB, long long strC) {
  __shared__ __align__(16) char smem[131072];
  const int bz = blockIdx.y;
  const int bid = blockIdx.x;
  const int swz = (bid & 7) * (nwg >> 3) + (bid >> 3);
  const int r0 = (swz / nwgx) * 256;
  const int c0 = (swz % nwgx) * 256;
  const int t = threadIdx.x, w = t >> 6, lane = t & 63;
  const int wm = w >> 2, wn = w & 3;
  const int fr = lane & 15, fh = lane >> 4;
  const int sl = (fh ^ (fr & 7)) << 4;
  const int srow = t >> 3;
  const int scb = (t & 7) ^ (srow & 7);
  const ushort_t* gA = A + strA * bz + (size_t)(r0 + srow) * lda + scb * 8;
  const ushort_t* gB = B + strB * bz + (size_t)(c0 + srow) * ldb + scb * 8;

  GEMM_BODY_PH

  CT* gC = C + strC * bz;
  const int cr = r0 + wm * 128 + fh * 4;
  const int cc = c0 + wn * 64 + fr;
#pragma unroll
  for (int m = 0; m < 8; ++m)
#pragma unroll
    for (int n = 0; n < 4; ++n)
#pragma unroll
      for (int j = 0; j < 4; ++j)
        storeC(&gC[(size_t)(cr + m * 16 + j) * ldc + cc + n * 16], acc[m][n][j]);
}

// ====== GLU-fused GEMM: r15 free-run structure (best measured @K=2048) =======
__global__ __launch_bounds__(512, 2) void gemm256_glu(
    const ushort_t* __restrict__ A, const ushort_t* __restrict__ B,
    ushort_t* __restrict__ C, int K, int lda, int ldb, int ldc,
    int nwgx, int nwg) {
  __shared__ __align__(16) char smem[131072];
  const int bid = blockIdx.x;
  const int swz = (bid & 7) * (nwg >> 3) + (bid >> 3);
  const int r0 = (swz / nwgx) * 256;
  const int c0 = (swz % nwgx) * 256;
  const int t = threadIdx.x, w = t >> 6, lane = t & 63;
  const int wm = w >> 2, wn = w & 3;
  const int fr = lane & 15, fh = lane >> 4;
  const int sl = (fh ^ (fr & 7)) << 4;
  const int ldsw = w * 1024;
  const int srow = t >> 3;
  const int scb = (t & 7) ^ (srow & 7);
  const int NT = K >> 6;
  const ushort_t* gA = A + (size_t)(r0 + srow) * lda + scb * 8;
  const ushort_t* gB = B + (size_t)(c0 + srow) * ldb + scb * 8;

  auto stage = [&](int tile, int isB, int h) {
    const ushort_t* g = isB ? gB : gA;
    const size_t ld = isB ? (size_t)ldb : (size_t)lda;
    char* lp = (char*)smem + (isB ? 65536 : 0) + ((tile & 1) << 15) + (h << 14) + ldsw;
    const ushort_t* src = g + (size_t)(h * 128) * ld + tile * 64;
    __builtin_amdgcn_global_load_lds((const AS1 void*)src, (AS3 void*)lp, 16, 0, 0);
    __builtin_amdgcn_global_load_lds((const AS1 void*)(src + 64 * ld),
                                     (AS3 void*)(lp + 8192), 16, 0, 0);
  };

  f32x4 acc[8][4] = {};

  stage(0, 0, 0); stage(0, 1, 0); stage(0, 0, 1); stage(0, 1, 1);
  asm volatile("s_waitcnt vmcnt(0)" ::: "memory");
  __builtin_amdgcn_sched_barrier(0);
  __builtin_amdgcn_s_barrier();
  __builtin_amdgcn_sched_barrier(0);

  const int aBase = wm * 16384 + fr * 128;
  const int bBase = 65536 + wn * 8192 + fr * 128;

  bf16x8 aX[4], aY[4], bX[4], bY[4];
  {
    const char* la0 = (const char*)smem + aBase;
    const char* lb0 = (const char*)smem + bBase;
#pragma unroll
    for (int m = 0; m < 4; ++m)
      aX[m] = *(const bf16x8*)(const void*)(la0 + m * 2048 + sl);
#pragma unroll
    for (int n = 0; n < 4; ++n)
      bX[n] = *(const bf16x8*)(const void*)(lb0 + n * 2048 + sl);
  }

  for (int kt = 0; kt < NT; ++kt) {
    const int buf = (kt & 1) << 15;
    const char* la = (const char*)smem + buf + aBase;
    const char* lb = (const char*)smem + buf + bBase;
#pragma unroll
    for (int m = 0; m < 4; ++m)
      aY[m] = *(const bf16x8*)(const void*)(la + (m + 4) * 2048 + sl);
    __builtin_amdgcn_sched_barrier(0);
    __builtin_amdgcn_s_setprio(1);
#pragma unroll
    for (int m = 0; m < 4; ++m)
#pragma unroll
      for (int n = 0; n < 4; ++n)
        acc[m][n] = __builtin_amdgcn_mfma_f32_16x16x32_bf16(aX[m], bX[n], acc[m][n], 0, 0, 0);
    __builtin_amdgcn_s_setprio(0);
    __builtin_amdgcn_sched_barrier(0);
#pragma unroll
    for (int m = 0; m < 4; ++m)
      aX[m] = *(const bf16x8*)(const void*)(la + m * 2048 + (sl ^ 64));
#pragma unroll
    for (int n = 0; n < 4; ++n)
      bY[n] = *(const bf16x8*)(const void*)(lb + n * 2048 + (sl ^ 64));
    if (kt + 1 < NT) {
      stage(kt + 1, 0, 0); stage(kt + 1, 1, 0);
      stage(kt + 1, 0, 1); stage(kt + 1, 1, 1);
    }
    __builtin_amdgcn_sched_barrier(0);
    __builtin_amdgcn_s_setprio(1);
#pragma unroll
    for (int m = 0; m < 4; ++m)
#pragma unroll
      for (int n = 0; n < 4; ++n)
        acc[m + 4][n] = __builtin_amdgcn_mfma_f32_16x16x32_bf16(aY[m], bX[n], acc[m + 4][n], 0, 0, 0);
    __builtin_amdgcn_s_setprio(0);
    __builtin_amdgcn_sched_barrier(0);
#pragma unroll
    for (int m = 0; m < 4; ++m)
      aY[m] = *(const bf16x8*)(const void*)(la + (m + 4) * 2048 + (sl ^ 64));
    __builtin_amdgcn_sched_barrier(0);
    __builtin_amdgcn_s_setprio(1);
#pragma unroll
    for (int m = 0; m < 4; ++m)
#pragma unroll
      for (int n = 0; n < 4; ++n)
        acc[m][n] = __builtin_amdgcn_mfma_f32_16x16x32_bf16(aX[m], bY[n], acc[m][n], 0, 0, 0);
    __builtin_amdgcn_s_setprio(0);
    __builtin_amdgcn_sched_barrier(0);
    __builtin_amdgcn_s_setprio(1);
#pragma unroll
    for (int m = 0; m < 4; ++m)
#pragma unroll
      for (int n = 0; n < 4; ++n)
        acc[m + 4][n] = __builtin_amdgcn_mfma_f32_16x16x32_bf16(aY[m], bY[n], acc[m + 4][n], 0, 0, 0);
    __builtin_amdgcn_s_setprio(0);
    if (kt + 1 < NT) {
      asm volatile("s_waitcnt vmcnt(0)" ::: "memory");
      __builtin_amdgcn_sched_barrier(0);
      __builtin_amdgcn_s_barrier();
      __builtin_amdgcn_sched_barrier(0);
      const int nbuf = ((kt + 1) & 1) << 15;
      const char* lan = (const char*)smem + nbuf + aBase;
      const char* lbn = (const char*)smem + nbuf + bBase;
#pragma unroll
      for (int m = 0; m < 4; ++m)
        aX[m] = *(const bf16x8*)(const void*)(lan + m * 2048 + sl);
#pragma unroll
      for (int n = 0; n < 4; ++n)
        bX[n] = *(const bf16x8*)(const void*)(lbn + n * 2048 + sl);
      __builtin_amdgcn_sched_barrier(0);
    }
  }

  const int cr = r0 + wm * 128 + fh * 4;
  const int cc2 = (c0 >> 1) + wn * 32 + fr;
#pragma unroll
  for (int m = 0; m < 8; ++m)
#pragma unroll
    for (int pp = 0; pp < 2; ++pp)
#pragma unroll
      for (int j = 0; j < 4; ++j) {
        float g1 = acc[m][2 * pp][j];
        float g3 = acc[m][2 * pp + 1][j];
        float hv = g1 / (1.0f + __expf(-g1)) * g3;
        C[(size_t)(cr + m * 16 + j) * ldc + cc2 + pp * 16] = f2bf(hv);
      }
}

// ---------------------------------------------------------------- host
extern "C" void kernel_launch(void* const* d_in, const int* in_sizes, int n_in,
                              void* d_out, int out_size, void* d_ws, size_t ws_size,
                              hipStream_t stream) {
  const float* x = (const float*)d_in[0];
  const float* wq = (const float*)d_in[1];
  const float* wk1 = (const float*)d_in[2];
  const float* wk2 = (const float*)d_in[3];
  const float* wk3 = (const float*)d_in[4];
  const float* wv1 = (const float*)d_in[5];
  const float* wv2 = (const float*)d_in[6];
  const float* wv3 = (const float*)d_in[7];
  const float* wo = (const float*)d_in[8];
  const float* fc = (const float*)d_in[9];
  const float* fs = (const float*)d_in[10];

  float* outp = (float*)d_out;
  float* okeys = outp + 8388608;
  float* ovals = outp + 12582912;

  char* p = (char*)d_ws;
  auto alloc = [&](size_t bytes) {
    char* r = p;
    p += (bytes + 255) & ~(size_t)255;
    return r;
  };
  ushort_t* xb = (ushort_t*)alloc(8388608ull * 2);
  ushort_t* w4T = (ushort_t*)alloc(4ull * 16777216 * 2);  // Bk' | Bv' (interleaved)
  ushort_t* w2T = (ushort_t*)alloc(2ull * 8388608 * 2);   // wk2T|wv2T
  ushort_t* wqoT = (ushort_t*)alloc(2ull * 4194304 * 2);  // wqT|woT
  ushort_t* qb = (ushort_t*)alloc(8388608ull * 2);
  ushort_t* kb = (ushort_t*)alloc(4194304ull * 2);
  ushort_t* vbT = (ushort_t*)alloc(4194304ull * 2);
  ushort_t* ob = (ushort_t*)alloc(8388608ull * 2);
  char* hreg = alloc(134217728ull);
  ushort_t* hbuf = (ushort_t*)hreg;                 // fused gate output [4096][8192]
  ushort_t* partQ16 = (ushort_t*)hreg;              // q bf16 partials (pre-gates)
  ushort_t* partWO16 = (ushort_t*)hreg;             // wo bf16 partials (post-attn)
  ushort_t* part16 = (ushort_t*)w4T;                // k2/v2 partials (dead Bk')

  ushort_t* Bk = w4T;
  ushort_t* Bv = w4T + 2ull * 16777216;
  ushort_t* wk2T = w2T;
  ushort_t* wv2T = w2T + 8388608;
  ushort_t* wqT = wqoT;
  ushort_t* woT = wqoT + 4194304;

  dim3 tb(32, 8);

  cast_f32_bf16<<<8192, 256, 0, stream>>>(x, xb);
  transpose_cast_glu<<<dim3(256, 64, 4), tb, 0, stream>>>(wk1, wk3, wv1, wv3,
                                                          w4T, 33554432);
  transpose_cast_b<<<dim3(32, 256, 2), tb, 0, stream>>>(wk2, wv2, wk2, wv2, w2T,
                                                        8192, 1024, 8388608);
  transpose_cast_b<<<dim3(64, 64, 2), tb, 0, stream>>>(wq, wo, wq, wo, wqoT,
                                                       2048, 2048, 4194304);

  // q projection: split-K z=2 -> bf16 partials, reduce (+rope+scale) -> qb
  gemm256<ushort_t><<<dim3(128, 2), 512, 0, stream>>>(
      xb, wqT, partQ16, 1024, 2048, 2048, 2048, 8, 128, 1024, 1024, 8388608);
  reduce_q<<<4096, 256, 0, stream>>>(partQ16, qb, fc, fs);

  // k gates: GLU-fused GEMM (free-run) -> hbuf; k2 split-K z=4 (phased); reduce
  gemm256_glu<<<dim3(1024, 1), 512, 0, stream>>>(
      xb, Bk, hbuf, 2048, 2048, 2048, 8192, 64, 1024);
  gemm256<ushort_t><<<dim3(64, 4), 512, 0, stream>>>(
      hbuf, wk2T, part16, 2048, 8192, 8192, 1024, 4, 64, 2048, 2048, 4194304);
  reduce_k<<<2048, 256, 0, stream>>>(part16, kb, okeys, fc, fs);

  // v gates (GLU-fused, free-run); v2 (phased); reduce (+transpose)
  gemm256_glu<<<dim3(1024, 1), 512, 0, stream>>>(
      xb, Bv, hbuf, 2048, 2048, 2048, 8192, 64, 1024);
  gemm256<ushort_t><<<dim3(64, 4), 512, 0, stream>>>(
      hbuf, wv2T, part16, 2048, 8192, 8192, 1024, 4, 64, 2048, 2048, 4194304);
  reduce_v<<<dim3(64, 4, 16), tb, 0, stream>>>(part16, ovals, vbT);

  // fused flash attention (512 blocks, 2/CU, balanced co-residency)
  flash_attn<<<dim3(16, 32), 256, 0, stream>>>(qb, kb, vbT, ob);

  // output projection: split-K z=2 (phased) -> bf16 partials, reduce -> outp
  gemm256<ushort_t><<<dim3(128, 2), 512, 0, stream>>>(
      ob, woT, partWO16, 1024, 2048, 2048, 2048, 8, 128, 1024, 1024, 8388608);
  reduce_wo<<<4096, 256, 0, stream>>>(partWO16, outp);

  (void)in_sizes; (void)n_in; (void)out_size; (void)ws_size;
}

// Round 18
// 933.632 us; speedup vs baseline: 1.0090x; 1.0090x over previous
//
#include <hip/hip_runtime.h>

typedef unsigned short ushort_t;
typedef __attribute__((ext_vector_type(4))) float f32x4;
typedef __attribute__((ext_vector_type(8))) __bf16 bf16x8;
typedef __attribute__((ext_vector_type(4))) unsigned short ushort4_t;
typedef __attribute__((ext_vector_type(8))) unsigned short ushort8_t;
typedef __attribute__((ext_vector_type(2))) unsigned int u32x2;

#define AS1 __attribute__((address_space(1)))
#define AS3 __attribute__((address_space(3)))

__device__ __forceinline__ float bf2f(ushort_t u) {
  unsigned int v = ((unsigned int)u) << 16;
  return __builtin_bit_cast(float, v);
}
__device__ __forceinline__ ushort_t f2bf(float f) {
  unsigned int u = __builtin_bit_cast(unsigned int, f);
  u += 0x7fffu + ((u >> 16) & 1u);
  return (ushort_t)(u >> 16);
}
__device__ __forceinline__ void storeC(float* p, float v) { *p = v; }
__device__ __forceinline__ void storeC(ushort_t* p, float v) { *p = f2bf(v); }

// ---------------------------------------------------------------- elementwise
__global__ __launch_bounds__(256) void cast_f32_bf16(const float* __restrict__ in,
                                                     ushort_t* __restrict__ outp) {
  size_t i = ((size_t)blockIdx.x * 256 + threadIdx.x) * 4;
  f32x4 v = *(const f32x4*)(const void*)&in[i];
  ushort4_t o;
#pragma unroll
  for (int j = 0; j < 4; ++j) o[j] = f2bf(v[j]);
  *(ushort4_t*)(void*)&outp[i] = o;
}

// batched W[K][N] f32 -> Wt[N][K] bf16 (plain)
__global__ __launch_bounds__(256) void transpose_cast_b(
    const float* __restrict__ W0, const float* __restrict__ W1,
    const float* __restrict__ W2, const float* __restrict__ W3,
    ushort_t* __restrict__ Wt, int K, int N, long long strT) {
  __shared__ float tile[32][33];
  const int z = blockIdx.z;
  const float* W = (z == 0) ? W0 : (z == 1) ? W1 : (z == 2) ? W2 : W3;
  ushort_t* out = Wt + (size_t)(strT * z);
  int n0 = blockIdx.x * 32, k0 = blockIdx.y * 32;
  int tx = threadIdx.x, ty = threadIdx.y;
#pragma unroll
  for (int i = 0; i < 4; ++i)
    tile[ty + 8 * i][tx] = W[(size_t)(k0 + ty + 8 * i) * N + n0 + tx];
  __syncthreads();
#pragma unroll
  for (int i = 0; i < 4; ++i)
    out[(size_t)(n0 + ty + 8 * i) * K + k0 + tx] = f2bf(tile[tx][ty + 8 * i]);
}

// gate-weight transpose with 16-col interleave for GLU-fused GEMM
__global__ __launch_bounds__(256) void transpose_cast_glu(
    const float* __restrict__ W1k, const float* __restrict__ W3k,
    const float* __restrict__ W1v, const float* __restrict__ W3v,
    ushort_t* __restrict__ out, long long strT) {
  __shared__ float tile[32][33];
  const int z = blockIdx.z;
  const float* W = (z == 0) ? W1k : (z == 1) ? W3k : (z == 2) ? W1v : W3v;
  ushort_t* o = out + (size_t)((z >> 1) * strT);
  const int zz = z & 1;
  int n0 = blockIdx.x * 32, k0 = blockIdx.y * 32;
  int tx = threadIdx.x, ty = threadIdx.y;
#pragma unroll
  for (int i = 0; i < 4; ++i)
    tile[ty + 8 * i][tx] = W[(size_t)(k0 + ty + 8 * i) * 8192 + n0 + tx];
  __syncthreads();
#pragma unroll
  for (int i = 0; i < 4; ++i) {
    int n = n0 + ty + 8 * i;
    int br = ((n >> 4) * 32) + zz * 16 + (n & 15);
    o[(size_t)br * 2048 + k0 + tx] = f2bf(tile[tx][ty + 8 * i]);
  }
}

// ------------------------------------------------- split-K reduce (bf16 parts)
__global__ __launch_bounds__(256) void reduce_q(const ushort_t* __restrict__ part,
                                                ushort_t* __restrict__ qb,
                                                const float* __restrict__ fc,
                                                const float* __restrict__ fs) {
  const float alpha = 0.08838834764831845f;  // 1/sqrt(128)
  int p = blockIdx.x * 256 + threadIdx.x;
  size_t e0 = (size_t)p * 8;
  int i0 = (int)((e0 & 127) >> 1);
  int s = (int)((e0 >> 11) & 2047);
  ushort8_t a = *(const ushort8_t*)(const void*)&part[e0];
  ushort8_t b = *(const ushort8_t*)(const void*)&part[e0 + 8388608];
  f32x4 c4 = *(const f32x4*)(const void*)&fc[s * 64 + i0];
  f32x4 s4 = *(const f32x4*)(const void*)&fs[s * 64 + i0];
  ushort8_t o;
#pragma unroll
  for (int j = 0; j < 4; ++j) {
    float xr = bf2f(a[2 * j]) + bf2f(b[2 * j]);
    float xi = bf2f(a[2 * j + 1]) + bf2f(b[2 * j + 1]);
    float c = c4[j] * alpha, sn = s4[j] * alpha;
    o[2 * j] = f2bf(xr * c - xi * sn);
    o[2 * j + 1] = f2bf(xr * sn + xi * c);
  }
  *(ushort8_t*)(void*)&qb[e0] = o;
}

__global__ __launch_bounds__(256) void reduce_k(const ushort_t* __restrict__ part,
                                                ushort_t* __restrict__ kb,
                                                float* __restrict__ okeys,
                                                const float* __restrict__ fc,
                                                const float* __restrict__ fs) {
  int p = blockIdx.x * 256 + threadIdx.x;
  size_t e0 = (size_t)p * 8;
  int i0 = (int)((e0 & 127) >> 1);
  int s = (int)((e0 >> 10) & 2047);
  ushort8_t a0 = *(const ushort8_t*)(const void*)&part[e0];
  ushort8_t a1 = *(const ushort8_t*)(const void*)&part[e0 + 4194304];
  ushort8_t a2 = *(const ushort8_t*)(const void*)&part[e0 + 8388608];
  ushort8_t a3 = *(const ushort8_t*)(const void*)&part[e0 + 12582912];
  f32x4 c4 = *(const f32x4*)(const void*)&fc[s * 64 + i0];
  f32x4 s4 = *(const f32x4*)(const void*)&fs[s * 64 + i0];
  ushort8_t o;
  f32x4 ov0, ov1;
#pragma unroll
  for (int j = 0; j < 4; ++j) {
    float xr = bf2f(a0[2 * j]) + bf2f(a1[2 * j]) + bf2f(a2[2 * j]) + bf2f(a3[2 * j]);
    float xi = bf2f(a0[2 * j + 1]) + bf2f(a1[2 * j + 1]) + bf2f(a2[2 * j + 1]) +
               bf2f(a3[2 * j + 1]);
    float c = c4[j], sn = s4[j];
    float orr = xr * c - xi * sn;
    float oi = xr * sn + xi * c;
    o[2 * j] = f2bf(orr);
    o[2 * j + 1] = f2bf(oi);
    if (j < 2) { ov0[2 * j] = orr; ov0[2 * j + 1] = oi; }
    else       { ov1[2 * (j - 2)] = orr; ov1[2 * (j - 2) + 1] = oi; }
  }
  *(ushort8_t*)(void*)&kb[e0] = o;
  *(f32x4*)(void*)&okeys[e0] = ov0;
  *(f32x4*)(void*)&okeys[e0 + 4] = ov1;
}

__global__ __launch_bounds__(256) void reduce_v(const ushort_t* __restrict__ part,
                                                float* __restrict__ ovals,
                                                ushort_t* __restrict__ vbT) {
  __shared__ ushort_t tile[32][33];
  int s0 = blockIdx.x * 32, d0 = blockIdx.y * 32, bk = blockIdx.z;
  int b = bk >> 3, kh = bk & 7;
  int tx = threadIdx.x, ty = threadIdx.y;
#pragma unroll
  for (int i = 0; i < 4; ++i) {
    int s = s0 + ty + 8 * i;
    size_t src = ((size_t)(b * 2048 + s)) * 1024 + kh * 128 + d0 + tx;
    float v = bf2f(part[src]) + bf2f(part[src + 4194304]) +
              bf2f(part[src + 8388608]) + bf2f(part[src + 12582912]);
    tile[ty + 8 * i][tx] = f2bf(v);
    ovals[src] = v;
  }
  __syncthreads();
#pragma unroll
  for (int i = 0; i < 4; ++i) {
    int d = d0 + ty + 8 * i;
    vbT[((size_t)bk * 128 + d) * 2048 + s0 + tx] = tile[tx][ty + 8 * i];
  }
}

// partO: [2][4096][2048] bf16 -> outp f32. 8 elems/thread -> grid 4096 ONLY.
__global__ __launch_bounds__(256) void reduce_wo(const ushort_t* __restrict__ part,
                                                 float* __restrict__ outp) {
  size_t e0 = ((size_t)blockIdx.x * 256 + threadIdx.x) * 8;
  ushort8_t a = *(const ushort8_t*)(const void*)&part[e0];
  ushort8_t b = *(const ushort8_t*)(const void*)&part[e0 + 8388608];
  f32x4 o0, o1;
#pragma unroll
  for (int j = 0; j < 4; ++j) {
    o0[j] = bf2f(a[j]) + bf2f(b[j]);
    o1[j] = bf2f(a[j + 4]) + bf2f(b[j + 4]);
  }
  *(f32x4*)(void*)&outp[e0] = o0;
  *(f32x4*)(void*)&outp[e0 + 4] = o1;
}

// ---------------------------------------------------------------- flash attn
__global__ __launch_bounds__(256) void flash_attn(
    const ushort_t* __restrict__ Q, const ushort_t* __restrict__ Kg,
    const ushort_t* __restrict__ VT, ushort_t* __restrict__ O) {
  __shared__ __align__(16) char smem[81920];
  const int xq = blockIdx.x;
  const int bh = blockIdx.y;
  const int qi = (bh & 16) ? (15 - xq) : xq;
  const int b = bh >> 4, h = bh & 15, kh = h >> 1;
  const int t = threadIdx.x, w = t >> 6, lane = t & 63;
  const int fr = lane & 15, fh = lane >> 4;
  const size_t kelem0 = ((size_t)b * 2048) * 1024 + kh * 128;
  const size_t velem0 = ((size_t)(b * 8 + kh)) * 128 * 2048;
  const size_t qrow0 = (size_t)b * 2048;

  size_t oK[4], oV[4];
#pragma unroll
  for (int qv = 0; qv < 4; ++qv) {
    int row = w * 16 + qv * 4 + (lane >> 4);
    oK[qv] = (size_t)row * 1024 + (((lane & 15) ^ (row & 7)) * 8);
    int rd = w * 32 + qv * 8 + (lane >> 3);
    oV[qv] = (size_t)rd * 2048 + (((lane & 7) ^ (rd & 7)) * 8);
  }

  auto stage = [&](int tile, int buf) {
    const size_t kc = (size_t)tile * 64 * 1024;
    const int vc = tile * 64;
    char* kd = smem + buf * 16384 + w * 4096;
    char* vd = smem + 32768 + buf * 16384 + w * 4096;
#pragma unroll
    for (int qv = 0; qv < 4; ++qv) {
      __builtin_amdgcn_global_load_lds((const AS1 void*)(Kg + kelem0 + kc + oK[qv]),
                                       (AS3 void*)(kd + qv * 1024), 16, 0, 0);
      __builtin_amdgcn_global_load_lds((const AS1 void*)(VT + velem0 + oV[qv] + vc),
                                       (AS3 void*)(vd + qv * 1024), 16, 0, 0);
    }
  };

  const int qw = qi * 128 + w * 32;
  const int nt = 2 * qi + 2;

  bf16x8 qF[2][4];
#pragma unroll
  for (int qt = 0; qt < 2; ++qt)
#pragma unroll
    for (int i = 0; i < 4; ++i)
      qF[qt][i] = *(const bf16x8*)(const void*)(
          Q + (qrow0 + qw + qt * 16 + fr) * 2048 + h * 128 + i * 32 + fh * 8);

  f32x4 acco[8][2] = {};
  float mrun[2] = {-1e30f, -1e30f};
  float lrun[2] = {0.0f, 0.0f};

  stage(0, 0);
#pragma unroll 1
  for (int tt = 0; tt < nt; ++tt) {
    const int c0 = tt * 64;
    if (tt + 1 < nt) {
      stage(tt + 1, (tt + 1) & 1);
      asm volatile("s_waitcnt vmcnt(8)" ::: "memory");
    } else {
      asm volatile("s_waitcnt vmcnt(0)" ::: "memory");
    }
    __builtin_amdgcn_sched_barrier(0);
    __builtin_amdgcn_s_barrier();
    const char* KL = smem + (tt & 1) * 16384;
    const char* VL = smem + 32768 + (tt & 1) * 16384;
    char* PL = smem + 65536 + w * 4096;
    if (c0 <= qw + 31) {
      f32x4 sacc[2][4] = {};
#pragma unroll
      for (int i = 0; i < 4; ++i)
#pragma unroll
        for (int mt = 0; mt < 4; ++mt) {
          bf16x8 kf = *(const bf16x8*)(const void*)(
              KL + (mt * 16 + fr) * 256 + (((i * 4 + fh) ^ (fr & 7)) * 16));
          sacc[0][mt] = __builtin_amdgcn_mfma_f32_16x16x32_bf16(kf, qF[0][i], sacc[0][mt], 0, 0, 0);
          sacc[1][mt] = __builtin_amdgcn_mfma_f32_16x16x32_bf16(kf, qF[1][i], sacc[1][mt], 0, 0, 0);
        }
      if (c0 + 63 > qw) {
#pragma unroll
        for (int qt = 0; qt < 2; ++qt) {
          int qg = qw + qt * 16 + fr;
#pragma unroll
          for (int mt = 0; mt < 4; ++mt)
#pragma unroll
            for (int j = 0; j < 4; ++j)
              if (c0 + mt * 16 + fh * 4 + j > qg) sacc[qt][mt][j] = -1e30f;
        }
      }
#pragma unroll
      for (int qt = 0; qt < 2; ++qt) {
        float mt_ = -1e30f;
#pragma unroll
        for (int mt = 0; mt < 4; ++mt)
#pragma unroll
          for (int j = 0; j < 4; ++j) mt_ = fmaxf(mt_, sacc[qt][mt][j]);
        mt_ = fmaxf(mt_, __shfl_xor(mt_, 16, 64));
        mt_ = fmaxf(mt_, __shfl_xor(mt_, 32, 64));
        float mnew = fmaxf(mrun[qt], mt_);
        float corr = __expf(mrun[qt] - mnew);
        mrun[qt] = mnew;
        float ps = 0.0f;
        float pv[4][4];
#pragma unroll
        for (int mt = 0; mt < 4; ++mt)
#pragma unroll
          for (int j = 0; j < 4; ++j) {
            float pe = __expf(sacc[qt][mt][j] - mnew);
            pv[mt][j] = pe;
            ps += pe;
          }
        ps += __shfl_xor(ps, 16, 64);
        ps += __shfl_xor(ps, 32, 64);
        lrun[qt] = lrun[qt] * corr + ps;
#pragma unroll
        for (int mt = 0; mt < 4; ++mt) {
          unsigned int u0, u1;
          asm("v_cvt_pk_bf16_f32 %0, %1, %2" : "=v"(u0) : "v"(pv[mt][0]), "v"(pv[mt][1]));
          asm("v_cvt_pk_bf16_f32 %0, %1, %2" : "=v"(u1) : "v"(pv[mt][2]), "v"(pv[mt][3]));
          u32x2 val;
          val[0] = u0;
          val[1] = u1;
          *(u32x2*)(void*)(PL + qt * 2048 + fr * 128 +
                           (((2 * mt + (fh >> 1)) ^ (fr & 7)) * 16) + (fh & 1) * 8) = val;
        }
#pragma unroll
        for (int dt = 0; dt < 8; ++dt) acco[dt][qt] *= corr;
      }
      bf16x8 pf[2][2];
#pragma unroll
      for (int qt = 0; qt < 2; ++qt)
#pragma unroll
        for (int ks = 0; ks < 2; ++ks)
          pf[qt][ks] = *(const bf16x8*)(const void*)(
              PL + qt * 2048 + fr * 128 + (((ks * 4 + fh) ^ (fr & 7)) * 16));
#pragma unroll
      for (int dt = 0; dt < 8; ++dt)
#pragma unroll
        for (int ks = 0; ks < 2; ++ks) {
          bf16x8 vf = *(const bf16x8*)(const void*)(
              VL + (dt * 16 + fr) * 128 + (((ks * 4 + fh) ^ (fr & 7)) * 16));
          acco[dt][0] = __builtin_amdgcn_mfma_f32_16x16x32_bf16(vf, pf[0][ks], acco[dt][0], 0, 0, 0);
          acco[dt][1] = __builtin_amdgcn_mfma_f32_16x16x32_bf16(vf, pf[1][ks], acco[dt][1], 0, 0, 0);
        }
    }
    __builtin_amdgcn_s_barrier();
  }
#pragma unroll
  for (int qt = 0; qt < 2; ++qt) {
    float inv = 1.0f / lrun[qt];
    const size_t rb = (qrow0 + qw + qt * 16 + fr) * 2048 + h * 128;
#pragma unroll
    for (int dt = 0; dt < 8; ++dt) {
      ushort4_t o4;
#pragma unroll
      for (int j = 0; j < 4; ++j) o4[j] = f2bf(acco[dt][qt][j] * inv);
      *(ushort4_t*)(void*)(O + rb + dt * 16 + fh * 4) = o4;
    }
  }
}

// ============ 256^2 GEMM, m201-style phased schedule (r16 best config) =======
#define GEMM_PHASE(ABUF, BBUF, Q, STAGE_STMT, TAIL_STMT)                        \
  {                                                                             \
    if ((Q) == 0) {                                                             \
      _Pragma("unroll") for (int nf = 0; nf < 4; ++nf) {                        \
        const char* bp = (BBUF) + ((wn * 64 + nf * 16 + fr) << 7);              \
        bF[nf][0] = *(const bf16x8*)(const void*)(bp + sl);                     \
        bF[nf][1] = *(const bf16x8*)(const void*)(bp + (sl ^ 64));              \
      }                                                                         \
    }                                                                           \
    _Pragma("unroll") for (int mi = 0; mi < 2; ++mi) {                          \
      const char* ap = (ABUF) + ((wm * 128 + ((Q)*2 + mi) * 16 + fr) << 7);     \
      aF[mi][0] = *(const bf16x8*)(const void*)(ap + sl);                       \
      aF[mi][1] = *(const bf16x8*)(const void*)(ap + (sl ^ 64));                \
    }                                                                           \
    STAGE_STMT;                                                                 \
    if ((Q) == 0) asm volatile("s_waitcnt lgkmcnt(8)" ::: "memory");            \
    __builtin_amdgcn_s_barrier();                                               \
    asm volatile("s_waitcnt lgkmcnt(0)" ::: "memory");                          \
    __builtin_amdgcn_sched_barrier(0);                                          \
    __builtin_amdgcn_s_setprio(1);                                              \
    _Pragma("unroll") for (int mi = 0; mi < 2; ++mi)                            \
      _Pragma("unroll") for (int nf = 0; nf < 4; ++nf) {                        \
        acc[(Q)*2 + mi][nf] = __builtin_amdgcn_mfma_f32_16x16x32_bf16(          \
            aF[mi][0], bF[nf][0], acc[(Q)*2 + mi][nf], 0, 0, 0);                \
        acc[(Q)*2 + mi][nf] = __builtin_amdgcn_mfma_f32_16x16x32_bf16(          \
            aF[mi][1], bF[nf][1], acc[(Q)*2 + mi][nf], 0, 0, 0);                \
      }                                                                         \
    __builtin_amdgcn_s_setprio(0);                                              \
    TAIL_STMT;                                                                  \
    __builtin_amdgcn_sched_barrier(0);                                          \
    __builtin_amdgcn_s_barrier();                                               \
  }

#define GEMM_BODY                                                               \
  f32x4 acc[8][4] = {};                                                         \
  const int NT = K >> 6;                                                        \
  const int NI = NT >> 1;                                                       \
  char* const A0 = (char*)smem;                                                 \
  char* const A1 = (char*)smem + 32768;                                         \
  char* const B0 = (char*)smem + 65536;                                         \
  char* const B1 = (char*)smem + 98304;                                         \
  auto stageA = [&](int tile, int h) {                                          \
    char* base = (char*)smem + ((tile & 1) << 15);                              \
    const ushort_t* src = gA + tile * 64 + (size_t)(h * 64) * lda;              \
    __builtin_amdgcn_global_load_lds((const AS1 void*)src,                      \
        (AS3 void*)(base + h * 8192 + w * 1024), 16, 0, 0);                     \
    __builtin_amdgcn_global_load_lds(                                           \
        (const AS1 void*)(src + (size_t)128 * lda),                             \
        (AS3 void*)(base + 16384 + h * 8192 + w * 1024), 16, 0, 0);             \
  };                                                                            \
  auto stageB = [&](int tile, int h) {                                          \
    char* base = (char*)smem + 65536 + ((tile & 1) << 15);                      \
    const ushort_t* src = gB + tile * 64 + (size_t)(h * 128) * ldb;             \
    __builtin_amdgcn_global_load_lds((const AS1 void*)src,                      \
        (AS3 void*)(base + h * 16384 + w * 1024), 16, 0, 0);                    \
    __builtin_amdgcn_global_load_lds(                                           \
        (const AS1 void*)(src + (size_t)64 * ldb),                              \
        (AS3 void*)(base + h * 16384 + 8192 + w * 1024), 16, 0, 0);             \
  };                                                                            \
  stageB(0, 0); stageB(0, 1); stageA(0, 0); stageA(0, 1);                       \
  stageB(1, 0); stageB(1, 1); stageA(1, 0);                                     \
  asm volatile("s_waitcnt vmcnt(6)" ::: "memory");                              \
  __builtin_amdgcn_sched_barrier(0);                                            \
  __builtin_amdgcn_s_barrier();                                                 \
  __builtin_amdgcn_sched_barrier(0);                                            \
  for (int i = 0; i < NI; ++i) {                                                \
    const int T1 = 2 * i + 1, T2 = 2 * i + 2, T3 = 2 * i + 3;                   \
    const bool s2 = T2 < NT, s3 = T3 < NT;                                      \
    bf16x8 bF[4][2], aF[2][2];                                                  \
    GEMM_PHASE(A0, B0, 0, { stageA(T1, 1); }, {})                               \
    GEMM_PHASE(A0, B0, 1, { if (s2) stageB(T2, 0); }, {})                       \
    GEMM_PHASE(A0, B0, 2, { if (s2) stageB(T2, 1); }, {})                       \
    GEMM_PHASE(A0, B0, 3, { if (s2) stageA(T2, 0); },                           \
               { if (s2) asm volatile("s_waitcnt vmcnt(6)" ::: "memory");       \
                 else    asm volatile("s_waitcnt vmcnt(0)" ::: "memory"); })    \
    GEMM_PHASE(A1, B1, 0, { if (s2) stageA(T2, 1); }, {})                       \
    GEMM_PHASE(A1, B1, 1, { if (s3) stageB(T3, 0); }, {})                       \
    GEMM_PHASE(A1, B1, 2, { if (s3) stageB(T3, 1); }, {})                       \
    GEMM_PHASE(A1, B1, 3, { if (s3) stageA(T3, 0); },                           \
               { if (s2) asm volatile("s_waitcnt vmcnt(6)" ::: "memory"); })    \
  }

template <typename CT>
__global__ __launch_bounds__(512, 2) void gemm256(
    const ushort_t* __restrict__ A, const ushort_t* __restrict__ B,
    CT* __restrict__ C, int K, int lda, int ldb, int ldc,
    int nwgx, int nwg, long long strA, long long strB, long long strC) {
  __shared__ __align__(16) char smem[131072];
  const int bz = blockIdx.y;
  const int bid = blockIdx.x;
  const int swz = (bid & 7) * (nwg >> 3) + (bid >> 3);
  const int r0 = (swz / nwgx) * 256;
  const int c0 = (swz % nwgx) * 256;
  const int t = threadIdx.x, w = t >> 6, lane = t & 63;
  const int wm = w >> 2, wn = w & 3;
  const int fr = lane & 15, fh = lane >> 4;
  const int sl = (fh ^ (fr & 7)) << 4;
  const int srow = t >> 3;
  const int scb = (t & 7) ^ (srow & 7);
  const ushort_t* gA = A + strA * bz + (size_t)(r0 + srow) * lda + scb * 8;
  const ushort_t* gB = B + strB * bz + (size_t)(c0 + srow) * ldb + scb * 8;

  GEMM_BODY

  CT* gC = C + strC * bz;
  const int cr = r0 + wm * 128 + fh * 4;
  const int cc = c0 + wn * 64 + fr;
#pragma unroll
  for (int m = 0; m < 8; ++m)
#pragma unroll
    for (int n = 0; n < 4; ++n)
#pragma unroll
      for (int j = 0; j < 4; ++j)
        storeC(&gC[(size_t)(cr + m * 16 + j) * ldc + cc + n * 16], acc[m][n][j]);
}

// GLU-fused epilogue variant (16-col-interleaved B')
__global__ __launch_bounds__(512, 2) void gemm256_glu(
    const ushort_t* __restrict__ A, const ushort_t* __restrict__ B,
    ushort_t* __restrict__ C, int K, int lda, int ldb, int ldc,
    int nwgx, int nwg) {
  __shared__ __align__(16) char smem[131072];
  const int bid = blockIdx.x;
  const int swz = (bid & 7) * (nwg >> 3) + (bid >> 3);
  const int r0 = (swz / nwgx) * 256;
  const int c0 = (swz % nwgx) * 256;
  const int t = threadIdx.x, w = t >> 6, lane = t & 63;
  const int wm = w >> 2, wn = w & 3;
  const int fr = lane & 15, fh = lane >> 4;
  const int sl = (fh ^ (fr & 7)) << 4;
  const int srow = t >> 3;
  const int scb = (t & 7) ^ (srow & 7);
  const ushort_t* gA = A + (size_t)(r0 + srow) * lda + scb * 8;
  const ushort_t* gB = B + (size_t)(c0 + srow) * ldb + scb * 8;

  GEMM_BODY

  const int cr = r0 + wm * 128 + fh * 4;
  const int cc2 = (c0 >> 1) + wn * 32 + fr;
#pragma unroll
  for (int m = 0; m < 8; ++m)
#pragma unroll
    for (int pp = 0; pp < 2; ++pp)
#pragma unroll
      for (int j = 0; j < 4; ++j) {
        float g1 = acc[m][2 * pp][j];
        float g3 = acc[m][2 * pp + 1][j];
        float hv = g1 / (1.0f + __expf(-g1)) * g3;
        C[(size_t)(cr + m * 16 + j) * ldc + cc2 + pp * 16] = f2bf(hv);
      }
}

// ---------------------------------------------------------------- host
extern "C" void kernel_launch(void* const* d_in, const int* in_sizes, int n_in,
                              void* d_out, int out_size, void* d_ws, size_t ws_size,
                              hipStream_t stream) {
  const float* x = (const float*)d_in[0];
  const float* wq = (const float*)d_in[1];
  const float* wk1 = (const float*)d_in[2];
  const float* wk2 = (const float*)d_in[3];
  const float* wk3 = (const float*)d_in[4];
  const float* wv1 = (const float*)d_in[5];
  const float* wv2 = (const float*)d_in[6];
  const float* wv3 = (const float*)d_in[7];
  const float* wo = (const float*)d_in[8];
  const float* fc = (const float*)d_in[9];
  const float* fs = (const float*)d_in[10];

  float* outp = (float*)d_out;
  float* okeys = outp + 8388608;
  float* ovals = outp + 12582912;

  char* p = (char*)d_ws;
  auto alloc = [&](size_t bytes) {
    char* r = p;
    p += (bytes + 255) & ~(size_t)255;
    return r;
  };
  ushort_t* xb = (ushort_t*)alloc(8388608ull * 2);
  ushort_t* w4T = (ushort_t*)alloc(4ull * 16777216 * 2);  // Bk' | Bv' (interleaved)
  ushort_t* w2T = (ushort_t*)alloc(2ull * 8388608 * 2);   // wk2T|wv2T
  ushort_t* wqoT = (ushort_t*)alloc(2ull * 4194304 * 2);  // wqT|woT
  ushort_t* qb = (ushort_t*)alloc(8388608ull * 2);
  ushort_t* kb = (ushort_t*)alloc(4194304ull * 2);
  ushort_t* vbT = (ushort_t*)alloc(4194304ull * 2);
  ushort_t* ob = (ushort_t*)alloc(8388608ull * 2);
  char* hreg = alloc(134217728ull);
  ushort_t* hbuf = (ushort_t*)hreg;                 // fused gate output [4096][8192]
  ushort_t* partQ16 = (ushort_t*)hreg;              // q bf16 partials (pre-gates)
  ushort_t* partWO16 = (ushort_t*)hreg;             // wo bf16 partials (post-attn)
  ushort_t* part16 = (ushort_t*)w4T;                // k2/v2 partials (dead Bk')

  ushort_t* Bk = w4T;
  ushort_t* Bv = w4T + 2ull * 16777216;
  ushort_t* wk2T = w2T;
  ushort_t* wv2T = w2T + 8388608;
  ushort_t* wqT = wqoT;
  ushort_t* woT = wqoT + 4194304;

  dim3 tb(32, 8);

  cast_f32_bf16<<<8192, 256, 0, stream>>>(x, xb);
  transpose_cast_glu<<<dim3(256, 64, 4), tb, 0, stream>>>(wk1, wk3, wv1, wv3,
                                                          w4T, 33554432);
  transpose_cast_b<<<dim3(32, 256, 2), tb, 0, stream>>>(wk2, wv2, wk2, wv2, w2T,
                                                        8192, 1024, 8388608);
  transpose_cast_b<<<dim3(64, 64, 2), tb, 0, stream>>>(wq, wo, wq, wo, wqoT,
                                                       2048, 2048, 4194304);

  // q projection: split-K z=2 -> bf16 partials, reduce (+rope+scale) -> qb
  gemm256<ushort_t><<<dim3(128, 2), 512, 0, stream>>>(
      xb, wqT, partQ16, 1024, 2048, 2048, 2048, 8, 128, 1024, 1024, 8388608);
  reduce_q<<<4096, 256, 0, stream>>>(partQ16, qb, fc, fs);

  // k gates: GLU-fused GEMM -> hbuf; k2 split-K z=4; reduce
  gemm256_glu<<<dim3(1024, 1), 512, 0, stream>>>(
      xb, Bk, hbuf, 2048, 2048, 2048, 8192, 64, 1024);
  gemm256<ushort_t><<<dim3(64, 4), 512, 0, stream>>>(
      hbuf, wk2T, part16, 2048, 8192, 8192, 1024, 4, 64, 2048, 2048, 4194304);
  reduce_k<<<2048, 256, 0, stream>>>(part16, kb, okeys, fc, fs);

  // v gates (GLU-fused); v2; reduce (+transpose)
  gemm256_glu<<<dim3(1024, 1), 512, 0, stream>>>(
      xb, Bv, hbuf, 2048, 2048, 2048, 8192, 64, 1024);
  gemm256<ushort_t><<<dim3(64, 4), 512, 0, stream>>>(
      hbuf, wv2T, part16, 2048, 8192, 8192, 1024, 4, 64, 2048, 2048, 4194304);
  reduce_v<<<dim3(64, 4, 16), tb, 0, stream>>>(part16, ovals, vbT);

  // fused flash attention (512 blocks, 2/CU, balanced co-residency)
  flash_attn<<<dim3(16, 32), 256, 0, stream>>>(qb, kb, vbT, ob);

  // output projection: split-K z=2 -> bf16 partials, reduce -> outp
  gemm256<ushort_t><<<dim3(128, 2), 512, 0, stream>>>(
      ob, woT, partWO16, 1024, 2048, 2048, 2048, 8, 128, 1024, 1024, 8388608);
  reduce_wo<<<4096, 256, 0, stream>>>(partWO16, outp);

  (void)in_sizes; (void)n_in; (void)out_size; (void)ws_size;
}